// Round 1
// baseline (4663.580 us; speedup 1.0000x reference)
//
#include <hip/hip_runtime.h>
#include <cstdint>

// Problem constants (fixed by the reference)
#define N_TRAIN 65536
#define N_TEST  4096
#define DIM     512
#define K_NN    5
#define NSEG    8
#define SEG     (N_TRAIN / NSEG)   // 8192 train cols per segment
#define TM      64                 // test rows per block
#define TN      128                // train cols per tile
#define BK      16                 // K tile

// ---------------------------------------------------------------------------
// Kernel 1: squared L2 norms of rows. One wave (64 lanes) per row.
// ---------------------------------------------------------------------------
__global__ __launch_bounds__(256) void norms_k(const float* __restrict__ X,
                                               float* __restrict__ out,
                                               int nrows) {
    int row  = blockIdx.x * 4 + (threadIdx.x >> 6);
    int lane = threadIdx.x & 63;
    if (row >= nrows) return;
    const float4* xp = (const float4*)(X + (size_t)row * DIM);
    float4 a = xp[lane];        // 512 floats = 128 float4; 2 per lane
    float4 b = xp[lane + 64];
    float s = a.x*a.x + a.y*a.y + a.z*a.z + a.w*a.w
            + b.x*b.x + b.y*b.y + b.z*b.z + b.w*b.w;
#pragma unroll
    for (int off = 32; off > 0; off >>= 1) s += __shfl_down(s, off, 64);
    if (lane == 0) out[row] = s;
}

// ---------------------------------------------------------------------------
// Kernel 2: fused distance GEMM + per-segment top-5.
// Block: 256 threads. Tile: TM=64 test rows x TN=128 train cols, BK=16.
// Microtile 4x8 per thread. Candidate key packs (f32bits(d2)<<32)|col so a
// single uint64 compare is lexicographic (dist, then lower index) — matches
// lax.top_k tie semantics since d2 >= 0.
// ---------------------------------------------------------------------------
__global__ __launch_bounds__(256) void knn_tile_k(
    const float* __restrict__ Xtr, const float* __restrict__ Xte,
    const float* __restrict__ x2,  const float* __restrict__ t2,
    unsigned long long* __restrict__ cand)
{
    __shared__ float As[BK][TM];                       // 4 KB, k-major
    __shared__ float Bs[BK][TN];                       // 8 KB, k-major
    __shared__ unsigned long long MB[TM][16 * K_NN];   // 40 KB merge buffer

    const int t   = threadIdx.x;
    const int ty  = t >> 4;         // 0..15: row group (4 rows)
    const int tx  = t & 15;         // 0..15: col group (8 cols)
    const int row0 = blockIdx.x * TM;
    const int seg0 = blockIdx.y * SEG;

    float t2r[4];
#pragma unroll
    for (int j = 0; j < 4; ++j) t2r[j] = t2[row0 + ty * 4 + j];

    unsigned long long top[4][K_NN];
#pragma unroll
    for (int j = 0; j < 4; ++j)
#pragma unroll
        for (int p = 0; p < K_NN; ++p) top[j][p] = ~0ull;

    // staging mapping: thread loads one float4 of A, two float4 of B
    const int srow = t >> 2;          // 0..63
    const int skq  = (t & 3) * 4;     // 0,4,8,12

    for (int ct = 0; ct < SEG / TN; ++ct) {
        const int col0 = seg0 + ct * TN;
        float acc[4][8] = {};

        for (int k0 = 0; k0 < DIM; k0 += BK) {
            float4 av  = *(const float4*)(Xte + (size_t)(row0 + srow) * DIM + k0 + skq);
            float4 bv0 = *(const float4*)(Xtr + (size_t)(col0 + srow) * DIM + k0 + skq);
            float4 bv1 = *(const float4*)(Xtr + (size_t)(col0 + 64 + srow) * DIM + k0 + skq);
            __syncthreads();   // previous compute done before overwrite
            As[skq + 0][srow] = av.x;  As[skq + 1][srow] = av.y;
            As[skq + 2][srow] = av.z;  As[skq + 3][srow] = av.w;
            Bs[skq + 0][srow] = bv0.x; Bs[skq + 1][srow] = bv0.y;
            Bs[skq + 2][srow] = bv0.z; Bs[skq + 3][srow] = bv0.w;
            Bs[skq + 0][srow + 64] = bv1.x; Bs[skq + 1][srow + 64] = bv1.y;
            Bs[skq + 2][srow + 64] = bv1.z; Bs[skq + 3][srow + 64] = bv1.w;
            __syncthreads();

#pragma unroll
            for (int k = 0; k < BK; ++k) {
                float4 a  = *(const float4*)&As[k][ty * 4];
                float4 b0 = *(const float4*)&Bs[k][tx * 8];
                float4 b1 = *(const float4*)&Bs[k][tx * 8 + 4];
                float a4[4] = {a.x, a.y, a.z, a.w};
                float b8[8] = {b0.x, b0.y, b0.z, b0.w, b1.x, b1.y, b1.z, b1.w};
#pragma unroll
                for (int j = 0; j < 4; ++j)
#pragma unroll
                    for (int l = 0; l < 8; ++l)
                        acc[j][l] = fmaf(a4[j], b8[l], acc[j][l]);
            }
        }

        // epilogue: form d2 and insert into per-thread top-5 (branchless shift)
#pragma unroll
        for (int j = 0; j < 4; ++j) {
#pragma unroll
            for (int l = 0; l < 8; ++l) {
                int col = col0 + tx * 8 + l;
                float d2 = fmaxf(t2r[j] + x2[col] - 2.0f * acc[j][l], 0.0f);
                unsigned long long key =
                    ((unsigned long long)__float_as_uint(d2) << 32) | (unsigned)col;
                if (key < top[j][4]) {
                    unsigned long long k0v = top[j][0], k1v = top[j][1];
                    unsigned long long k2v = top[j][2], k3v = top[j][3];
                    top[j][0] = (key < k0v) ? key : k0v;
                    top[j][1] = (key < k0v) ? k0v : ((key < k1v) ? key : k1v);
                    top[j][2] = (key < k1v) ? k1v : ((key < k2v) ? key : k2v);
                    top[j][3] = (key < k2v) ? k2v : ((key < k3v) ? key : k3v);
                    top[j][4] = (key < k3v) ? k3v : key;
                }
            }
        }
    }

    // merge across the 16 col-group threads per row
#pragma unroll
    for (int j = 0; j < 4; ++j)
#pragma unroll
        for (int p = 0; p < K_NN; ++p)
            MB[ty * 4 + j][tx * K_NN + p] = top[j][p];
    __syncthreads();

    if (t < TM) {
        unsigned long long last = 0;  // keys are distinct (col in low bits) and > 0
        for (int p = 0; p < K_NN; ++p) {
            unsigned long long best = ~0ull;
            for (int q = 0; q < 16 * K_NN; ++q) {
                unsigned long long v = MB[t][q];
                if (v > last && v < best) best = v;
            }
            cand[(size_t)(row0 + t) * (NSEG * K_NN) + blockIdx.y * K_NN + p] = best;
            last = best;
        }
    }
}

// ---------------------------------------------------------------------------
// Kernel 3: merge per-segment candidates (40 -> 5) and mode vote.
// ---------------------------------------------------------------------------
__global__ __launch_bounds__(256) void knn_final_k(
    const unsigned long long* __restrict__ cand,
    const int* __restrict__ y, int* __restrict__ out)
{
    int r = blockIdx.x * 256 + threadIdx.x;
    if (r >= N_TEST) return;
    const unsigned long long* c = cand + (size_t)r * (NSEG * K_NN);

    unsigned long long v[NSEG * K_NN];
#pragma unroll
    for (int i = 0; i < NSEG * K_NN; ++i) v[i] = c[i];

    int labs[K_NN];
    unsigned long long last = 0;
    for (int p = 0; p < K_NN; ++p) {
        unsigned long long best = ~0ull;
#pragma unroll
        for (int i = 0; i < NSEG * K_NN; ++i) {
            unsigned long long vv = v[i];
            if (vv > last && vv < best) best = vv;
        }
        labs[p] = y[(unsigned)(best & 0xffffffffu)];
        last = best;
    }

    // mode, smallest label wins ties (matches reference where/min construction)
    int bestLab = 0x7fffffff, bestCnt = 0;
#pragma unroll
    for (int p = 0; p < K_NN; ++p) {
        int cnt = 0;
#pragma unroll
        for (int q = 0; q < K_NN; ++q) cnt += (labs[q] == labs[p]) ? 1 : 0;
        if (cnt > bestCnt || (cnt == bestCnt && labs[p] < bestLab)) {
            bestCnt = cnt; bestLab = labs[p];
        }
    }
    out[r] = bestLab;
}

// ---------------------------------------------------------------------------
// Workspace layout (needs ~1.6 MB):
//   [0, 256KB)        x2   : 65536 f32 train norms
//   [256KB, 272KB)    t2   : 4096 f32 test norms
//   [272KB, ~1.6MB)   cand : 4096 * 8 * 5 uint64 candidate keys
// ---------------------------------------------------------------------------
extern "C" void kernel_launch(void* const* d_in, const int* in_sizes, int n_in,
                              void* d_out, int out_size, void* d_ws, size_t ws_size,
                              hipStream_t stream) {
    const float* Xtr = (const float*)d_in[0];
    const float* Xte = (const float*)d_in[1];
    const int*   y   = (const int*)d_in[2];
    int* out = (int*)d_out;

    char* ws = (char*)d_ws;
    float* x2 = (float*)ws;
    float* t2 = (float*)(ws + 262144);
    unsigned long long* cand = (unsigned long long*)(ws + 278528);

    norms_k<<<N_TRAIN / 4, 256, 0, stream>>>(Xtr, x2, N_TRAIN);
    norms_k<<<N_TEST / 4, 256, 0, stream>>>(Xte, t2, N_TEST);
    knn_tile_k<<<dim3(N_TEST / TM, NSEG), 256, 0, stream>>>(Xtr, Xte, x2, t2, cand);
    knn_final_k<<<N_TEST / 256, 256, 0, stream>>>(cand, y, out);
}

// Round 2
// 1250.642 us; speedup vs baseline: 3.7289x; 3.7289x over previous
//
#include <hip/hip_runtime.h>
#include <cstdint>

// Problem constants (fixed by the reference)
#define N_TRAIN 65536
#define N_TEST  4096
#define DIM     512
#define K_NN    5
#define NSEG    8
#define SEG     (N_TRAIN / NSEG)   // 8192 train cols per segment

// MFMA path tile config
#define GTM 128      // test rows per block
#define GTN 128      // train cols per tile
#define GBK 32       // K per step (one 16x16x32 MFMA)
#define NCAND 80     // candidates per test row (8 seg x 2 halves x 5)

typedef __bf16 bf16x8 __attribute__((ext_vector_type(8)));
typedef float  f32x4  __attribute__((ext_vector_type(4)));

#define GLDS16(g, l)                                                          \
    __builtin_amdgcn_global_load_lds(                                         \
        (__attribute__((address_space(1))) void*)(g),                         \
        (__attribute__((address_space(3))) void*)(l), 16, 0, 0)

// ---------------------------------------------------------------------------
// Kernel 1: squared L2 norms of rows. One wave (64 lanes) per row.
// ---------------------------------------------------------------------------
__global__ __launch_bounds__(256) void norms_k(const float* __restrict__ X,
                                               float* __restrict__ out,
                                               int nrows) {
    int row  = blockIdx.x * 4 + (threadIdx.x >> 6);
    int lane = threadIdx.x & 63;
    if (row >= nrows) return;
    const float4* xp = (const float4*)(X + (size_t)row * DIM);
    float4 a = xp[lane];
    float4 b = xp[lane + 64];
    float s = a.x*a.x + a.y*a.y + a.z*a.z + a.w*a.w
            + b.x*b.x + b.y*b.y + b.z*b.z + b.w*b.w;
#pragma unroll
    for (int off = 32; off > 0; off >>= 1) s += __shfl_down(s, off, 64);
    if (lane == 0) out[row] = s;
}

// ---------------------------------------------------------------------------
// Kernel 2: fp32 -> bf16 (RNE) conversion, 8 elements per thread.
// ---------------------------------------------------------------------------
__device__ inline unsigned short f2bf(float x) {
    unsigned u = __float_as_uint(x);
    return (unsigned short)((u + 0x7FFFu + ((u >> 16) & 1u)) >> 16);
}

__global__ __launch_bounds__(256) void cvt_k(const float* __restrict__ in,
                                             unsigned short* __restrict__ out,
                                             int n8) {
    int i = blockIdx.x * 256 + threadIdx.x;
    if (i >= n8) return;
    const float4* p = (const float4*)in + (size_t)i * 2;
    float4 a = p[0], b = p[1];
    uint4 v;
    v.x = (unsigned)f2bf(a.x) | ((unsigned)f2bf(a.y) << 16);
    v.y = (unsigned)f2bf(a.z) | ((unsigned)f2bf(a.w) << 16);
    v.z = (unsigned)f2bf(b.x) | ((unsigned)f2bf(b.y) << 16);
    v.w = (unsigned)f2bf(b.z) | ((unsigned)f2bf(b.w) << 16);
    *((uint4*)out + i) = v;
}

// ---------------------------------------------------------------------------
// top-5 insertion (sorted ascending), uint64 keys
// ---------------------------------------------------------------------------
__device__ inline void ins5(unsigned long long key, unsigned long long* top) {
    if (key < top[4]) {
        unsigned long long k0 = top[0], k1 = top[1], k2 = top[2], k3 = top[3];
        top[0] = key < k0 ? key : k0;
        top[1] = key < k0 ? k0 : (key < k1 ? key : k1);
        top[2] = key < k1 ? k1 : (key < k2 ? key : k2);
        top[3] = key < k2 ? k2 : (key < k3 ? key : k3);
        top[4] = key < k3 ? k3 : key;
    }
}

// order-preserving float -> uint map (handles negatives)
__device__ inline unsigned fmono(float v) {
    unsigned u = __float_as_uint(v);
    return (u & 0x80000000u) ? ~u : (u | 0x80000000u);
}

// ---------------------------------------------------------------------------
// Kernel 3: bf16 MFMA distance GEMM + per-(row,seg,half) approx top-5.
// Block 256 thr (4 waves, 2x2 of 64x64). Tile 128x128, BK=32.
// v = x2[col] - 2*cross  (t2 is constant per row -> dropped for ordering).
// ---------------------------------------------------------------------------
__global__ __launch_bounds__(256, 3) void knn_mfma_k(
    const unsigned short* __restrict__ Xtrb,  // bf16 bits [N_TRAIN][DIM]
    const unsigned short* __restrict__ Xteb,  // bf16 bits [N_TEST][DIM]
    const float* __restrict__ x2,
    unsigned long long* __restrict__ cand)    // [N_TEST][NCAND]
{
    __shared__ __align__(16) unsigned short As[GTM * GBK];  // [row][k] 8 KB
    __shared__ __align__(16) unsigned short Bs[GTN * GBK];  // [col][k] 8 KB
    __shared__ __align__(16) float Ds[GTM * 68];            // [row][c<64 +pad] 34 KB

    const int t     = threadIdx.x;
    const int lane  = t & 63;
    const int w     = t >> 6;
    const int wr    = w >> 1, wc = w & 1;
    const int col_l = lane & 15, quad = lane >> 4;
    const int row0  = blockIdx.x * GTM;
    const int seg0  = blockIdx.y * SEG;

    const int selrow = t >> 1;   // 0..127
    const int selh   = t & 1;    // 32-col half within the 64-col pass

    unsigned long long top[K_NN];
#pragma unroll
    for (int p = 0; p < K_NN; ++p) top[p] = ~0ull;

    for (int ct = 0; ct < SEG / GTN; ++ct) {
        const int col0 = seg0 + ct * GTN;
        f32x4 acc[4][4];
#pragma unroll
        for (int mt = 0; mt < 4; ++mt)
#pragma unroll
            for (int nt = 0; nt < 4; ++nt)
                acc[mt][nt] = (f32x4){0.f, 0.f, 0.f, 0.f};

        for (int k0 = 0; k0 < DIM; k0 += GBK) {
            __syncthreads();   // prior frag reads done before overwrite
            // stage A and B tiles: slot = j*256 + t; row=slot>>2, kchunk=(slot&3)*8
            {
                int s0 = t, s1 = 256 + t;
                const unsigned short* gA0 =
                    Xteb + (size_t)(row0 + (s0 >> 2)) * DIM + k0 + (s0 & 3) * 8;
                const unsigned short* gA1 =
                    Xteb + (size_t)(row0 + (s1 >> 2)) * DIM + k0 + (s1 & 3) * 8;
                const unsigned short* gB0 =
                    Xtrb + (size_t)(col0 + (s0 >> 2)) * DIM + k0 + (s0 & 3) * 8;
                const unsigned short* gB1 =
                    Xtrb + (size_t)(col0 + (s1 >> 2)) * DIM + k0 + (s1 & 3) * 8;
                GLDS16(gA0, &As[(0 * 256 + w * 64) * 8]);
                GLDS16(gA1, &As[(1 * 256 + w * 64) * 8]);
                GLDS16(gB0, &Bs[(0 * 256 + w * 64) * 8]);
                GLDS16(gB1, &Bs[(1 * 256 + w * 64) * 8]);
            }
            __syncthreads();   // data arrived (compiler drains vmcnt before barrier)

            bf16x8 af[4], bfr[4];
#pragma unroll
            for (int mt = 0; mt < 4; ++mt)
                af[mt] = *(const bf16x8*)&As[(wr * 64 + mt * 16 + col_l) * GBK + quad * 8];
#pragma unroll
            for (int nt = 0; nt < 4; ++nt)
                bfr[nt] = *(const bf16x8*)&Bs[(wc * 64 + nt * 16 + col_l) * GBK + quad * 8];
#pragma unroll
            for (int mt = 0; mt < 4; ++mt)
#pragma unroll
                for (int nt = 0; nt < 4; ++nt)
                    acc[mt][nt] = __builtin_amdgcn_mfma_f32_16x16x32_bf16(
                        af[mt], bfr[nt], acc[mt][nt], 0, 0, 0);
        }

        // epilogue: two 64-col half passes through Ds
#pragma unroll 1
        for (int p = 0; p < 2; ++p) {
            __syncthreads();   // previous pass's selection reads done
            if (wc == p) {
#pragma unroll
                for (int nt = 0; nt < 4; ++nt) {
                    int c = nt * 16 + col_l;                // 0..63 within half
                    float xv = x2[col0 + p * 64 + c];
#pragma unroll
                    for (int mt = 0; mt < 4; ++mt) {
                        int rb = wr * 64 + mt * 16 + quad * 4;
                        f32x4 a = acc[mt][nt];
                        Ds[(rb + 0) * 68 + c] = fmaf(-2.f, a.x, xv);
                        Ds[(rb + 1) * 68 + c] = fmaf(-2.f, a.y, xv);
                        Ds[(rb + 2) * 68 + c] = fmaf(-2.f, a.z, xv);
                        Ds[(rb + 3) * 68 + c] = fmaf(-2.f, a.w, xv);
                    }
                }
            }
            __syncthreads();
            // selection: 2 threads per row, each scans 32 cols of this half
            int cb = selh * 32;
            int colbase = col0 + p * 64 + cb;
#pragma unroll
            for (int j = 0; j < 32; j += 4) {
                f32x4 v = *(const f32x4*)&Ds[selrow * 68 + cb + j];
                unsigned long long key;
                key = ((unsigned long long)fmono(v.x) << 32) | (unsigned)(colbase + j + 0);
                ins5(key, top);
                key = ((unsigned long long)fmono(v.y) << 32) | (unsigned)(colbase + j + 1);
                ins5(key, top);
                key = ((unsigned long long)fmono(v.z) << 32) | (unsigned)(colbase + j + 2);
                ins5(key, top);
                key = ((unsigned long long)fmono(v.w) << 32) | (unsigned)(colbase + j + 3);
                ins5(key, top);
            }
        }
    }

    // write candidates: per (row, seg): 2 threads x 5 keys
    unsigned long long* cr =
        cand + (size_t)(row0 + selrow) * NCAND + blockIdx.y * 10 + selh * 5;
#pragma unroll
    for (int p = 0; p < K_NN; ++p) cr[p] = top[p];
}

// ---------------------------------------------------------------------------
// Kernel 4: exact fp32 rescore of the 80 candidates. One wave per test row.
// Overwrites cand keys with ((bits(exact d2)<<32)|col).
// ---------------------------------------------------------------------------
__global__ __launch_bounds__(256) void rescore_k(
    const float* __restrict__ Xtr, const float* __restrict__ Xte,
    const float* __restrict__ x2,  const float* __restrict__ t2,
    unsigned long long* __restrict__ cand)
{
    int row  = blockIdx.x * 4 + (threadIdx.x >> 6);
    int lane = threadIdx.x & 63;
    const float4* te = (const float4*)(Xte + (size_t)row * DIM);
    float4 e0 = te[lane * 2], e1 = te[lane * 2 + 1];
    float t2r = t2[row];
    unsigned long long* cr = cand + (size_t)row * NCAND;

    for (int i = 0; i < NCAND; ++i) {
        unsigned col = (unsigned)(cr[i] & 0xffffffffu);
        const float4* tr = (const float4*)(Xtr + (size_t)col * DIM);
        float4 p = tr[lane * 2], q = tr[lane * 2 + 1];
        float s = e0.x * p.x;
        s = fmaf(e0.y, p.y, s); s = fmaf(e0.z, p.z, s); s = fmaf(e0.w, p.w, s);
        s = fmaf(e1.x, q.x, s); s = fmaf(e1.y, q.y, s);
        s = fmaf(e1.z, q.z, s); s = fmaf(e1.w, q.w, s);
#pragma unroll
        for (int off = 32; off > 0; off >>= 1) s += __shfl_xor(s, off, 64);
        float d2 = fmaxf(t2r + x2[col] - 2.0f * s, 0.0f);
        if (lane == 0)
            cr[i] = ((unsigned long long)__float_as_uint(d2) << 32) | col;
    }
}

// ---------------------------------------------------------------------------
// Kernel 5: exact top-5 of 80 + mode vote (smallest label wins ties).
// ---------------------------------------------------------------------------
__global__ __launch_bounds__(256) void final_k(
    const unsigned long long* __restrict__ cand,
    const int* __restrict__ y, int* __restrict__ out)
{
    int r = blockIdx.x * 256 + threadIdx.x;
    if (r >= N_TEST) return;
    const unsigned long long* cr = cand + (size_t)r * NCAND;

    unsigned long long top[K_NN];
#pragma unroll
    for (int p = 0; p < K_NN; ++p) top[p] = ~0ull;
#pragma unroll 8
    for (int i = 0; i < NCAND; ++i) ins5(cr[i], top);

    int labs[K_NN];
#pragma unroll
    for (int p = 0; p < K_NN; ++p) labs[p] = y[(unsigned)(top[p] & 0xffffffffu)];

    int bestLab = 0x7fffffff, bestCnt = 0;
#pragma unroll
    for (int p = 0; p < K_NN; ++p) {
        int cnt = 0;
#pragma unroll
        for (int q = 0; q < K_NN; ++q) cnt += (labs[q] == labs[p]) ? 1 : 0;
        if (cnt > bestCnt || (cnt == bestCnt && labs[p] < bestLab)) {
            bestCnt = cnt; bestLab = labs[p];
        }
    }
    out[r] = bestLab;
}

// ===========================================================================
// Fallback fp32 path (round-1, verified) in case ws_size is too small.
// ===========================================================================
#define FTM 64
#define FTN 128
#define FBK 16

__global__ __launch_bounds__(256) void knn_tile_k(
    const float* __restrict__ Xtr, const float* __restrict__ Xte,
    const float* __restrict__ x2,  const float* __restrict__ t2,
    unsigned long long* __restrict__ cand)
{
    __shared__ float As[FBK][FTM];
    __shared__ float Bs[FBK][FTN];
    __shared__ unsigned long long MB[FTM][16 * K_NN];

    const int t   = threadIdx.x;
    const int ty  = t >> 4;
    const int tx  = t & 15;
    const int row0 = blockIdx.x * FTM;
    const int seg0 = blockIdx.y * SEG;

    float t2r[4];
#pragma unroll
    for (int j = 0; j < 4; ++j) t2r[j] = t2[row0 + ty * 4 + j];

    unsigned long long top[4][K_NN];
#pragma unroll
    for (int j = 0; j < 4; ++j)
#pragma unroll
        for (int p = 0; p < K_NN; ++p) top[j][p] = ~0ull;

    const int srow = t >> 2;
    const int skq  = (t & 3) * 4;

    for (int ct = 0; ct < SEG / FTN; ++ct) {
        const int col0 = seg0 + ct * FTN;
        float acc[4][8] = {};

        for (int k0 = 0; k0 < DIM; k0 += FBK) {
            float4 av  = *(const float4*)(Xte + (size_t)(row0 + srow) * DIM + k0 + skq);
            float4 bv0 = *(const float4*)(Xtr + (size_t)(col0 + srow) * DIM + k0 + skq);
            float4 bv1 = *(const float4*)(Xtr + (size_t)(col0 + 64 + srow) * DIM + k0 + skq);
            __syncthreads();
            As[skq + 0][srow] = av.x;  As[skq + 1][srow] = av.y;
            As[skq + 2][srow] = av.z;  As[skq + 3][srow] = av.w;
            Bs[skq + 0][srow] = bv0.x; Bs[skq + 1][srow] = bv0.y;
            Bs[skq + 2][srow] = bv0.z; Bs[skq + 3][srow] = bv0.w;
            Bs[skq + 0][srow + 64] = bv1.x; Bs[skq + 1][srow + 64] = bv1.y;
            Bs[skq + 2][srow + 64] = bv1.z; Bs[skq + 3][srow + 64] = bv1.w;
            __syncthreads();

#pragma unroll
            for (int k = 0; k < FBK; ++k) {
                float4 a  = *(const float4*)&As[k][ty * 4];
                float4 b0 = *(const float4*)&Bs[k][tx * 8];
                float4 b1 = *(const float4*)&Bs[k][tx * 8 + 4];
                float a4[4] = {a.x, a.y, a.z, a.w};
                float b8[8] = {b0.x, b0.y, b0.z, b0.w, b1.x, b1.y, b1.z, b1.w};
#pragma unroll
                for (int j = 0; j < 4; ++j)
#pragma unroll
                    for (int l = 0; l < 8; ++l)
                        acc[j][l] = fmaf(a4[j], b8[l], acc[j][l]);
            }
        }

#pragma unroll
        for (int j = 0; j < 4; ++j) {
#pragma unroll
            for (int l = 0; l < 8; ++l) {
                int col = col0 + tx * 8 + l;
                float d2 = fmaxf(t2r[j] + x2[col] - 2.0f * acc[j][l], 0.0f);
                unsigned long long key =
                    ((unsigned long long)__float_as_uint(d2) << 32) | (unsigned)col;
                ins5(key, top[j]);
            }
        }
    }

#pragma unroll
    for (int j = 0; j < 4; ++j)
#pragma unroll
        for (int p = 0; p < K_NN; ++p)
            MB[ty * 4 + j][tx * K_NN + p] = top[j][p];
    __syncthreads();

    if (t < FTM) {
        unsigned long long last = 0;
        for (int p = 0; p < K_NN; ++p) {
            unsigned long long best = ~0ull;
            for (int q = 0; q < 16 * K_NN; ++q) {
                unsigned long long v = MB[t][q];
                if (v > last && v < best) best = v;
            }
            cand[(size_t)(row0 + t) * (NSEG * K_NN) + blockIdx.y * K_NN + p] = best;
            last = best;
        }
    }
}

__global__ __launch_bounds__(256) void knn_final_k(
    const unsigned long long* __restrict__ cand,
    const int* __restrict__ y, int* __restrict__ out)
{
    int r = blockIdx.x * 256 + threadIdx.x;
    if (r >= N_TEST) return;
    const unsigned long long* c = cand + (size_t)r * (NSEG * K_NN);

    unsigned long long top[K_NN];
#pragma unroll
    for (int p = 0; p < K_NN; ++p) top[p] = ~0ull;
#pragma unroll
    for (int i = 0; i < NSEG * K_NN; ++i) ins5(c[i], top);

    int labs[K_NN];
#pragma unroll
    for (int p = 0; p < K_NN; ++p) labs[p] = y[(unsigned)(top[p] & 0xffffffffu)];

    int bestLab = 0x7fffffff, bestCnt = 0;
#pragma unroll
    for (int p = 0; p < K_NN; ++p) {
        int cnt = 0;
#pragma unroll
        for (int q = 0; q < K_NN; ++q) cnt += (labs[q] == labs[p]) ? 1 : 0;
        if (cnt > bestCnt || (cnt == bestCnt && labs[p] < bestLab)) {
            bestCnt = cnt; bestLab = labs[p];
        }
    }
    out[r] = bestLab;
}

// ---------------------------------------------------------------------------
// Workspace layout (MFMA path), bytes:
//   [0,        262144)   x2     : 65536 f32
//   [262144,   278528)   t2     : 4096 f32
//   [278528,  2899968)   cand   : 4096 * 80 u64
//   [3145728, 7340032)   Xte_bf : 4096*512 bf16
//   [7340032, 74448896)  Xtr_bf : 65536*512 bf16
// ---------------------------------------------------------------------------
extern "C" void kernel_launch(void* const* d_in, const int* in_sizes, int n_in,
                              void* d_out, int out_size, void* d_ws, size_t ws_size,
                              hipStream_t stream) {
    const float* Xtr = (const float*)d_in[0];
    const float* Xte = (const float*)d_in[1];
    const int*   y   = (const int*)d_in[2];
    int* out = (int*)d_out;

    char* ws = (char*)d_ws;
    float* x2 = (float*)ws;
    float* t2 = (float*)(ws + 262144);
    unsigned long long* cand = (unsigned long long*)(ws + 278528);

    const size_t NEED = 74448896;

    norms_k<<<N_TRAIN / 4, 256, 0, stream>>>(Xtr, x2, N_TRAIN);
    norms_k<<<N_TEST / 4, 256, 0, stream>>>(Xte, t2, N_TEST);

    if (ws_size >= NEED) {
        unsigned short* Xteb = (unsigned short*)(ws + 3145728);
        unsigned short* Xtrb = (unsigned short*)(ws + 7340032);

        cvt_k<<<(N_TRAIN * DIM / 8 + 255) / 256, 256, 0, stream>>>(Xtr, Xtrb, N_TRAIN * DIM / 8);
        cvt_k<<<(N_TEST * DIM / 8 + 255) / 256, 256, 0, stream>>>(Xte, Xteb, N_TEST * DIM / 8);

        knn_mfma_k<<<dim3(N_TEST / GTM, NSEG), 256, 0, stream>>>(Xtrb, Xteb, x2, cand);
        rescore_k<<<N_TEST / 4, 256, 0, stream>>>(Xtr, Xte, x2, t2, cand);
        final_k<<<N_TEST / 256, 256, 0, stream>>>(cand, y, out);
    } else {
        // fp32 fallback (round-1 verified path); cand here is [N_TEST][40]
        knn_tile_k<<<dim3(N_TEST / FTM, NSEG), 256, 0, stream>>>(Xtr, Xte, x2, t2, cand);
        knn_final_k<<<N_TEST / 256, 256, 0, stream>>>(cand, y, out);
    }
}

// Round 4
// 842.350 us; speedup vs baseline: 5.5364x; 1.4847x over previous
//
#include <hip/hip_runtime.h>
#include <cstdint>

// Problem constants (fixed by the reference)
#define N_TRAIN 65536
#define N_TEST  4096
#define DIM     512
#define K_NN    5
#define NSEG    16
#define SEG     (N_TRAIN / NSEG)   // 4096 train cols per segment

// MFMA path tile config
#define GTM 128      // test rows per block
#define GTN 128      // train cols per tile
#define GBK 32       // K per step (one 16x16x32 MFMA)
#define NCAND (NSEG * K_NN)                 // 80 candidates per test row
#define NSTEP ((SEG / GTN) * (DIM / GBK))   // 32 col-tiles * 16 k-steps = 512

typedef __bf16 bf16x8 __attribute__((ext_vector_type(8)));
typedef float  f32x4  __attribute__((ext_vector_type(4)));

#define GLDS16(g, l)                                                          \
    __builtin_amdgcn_global_load_lds(                                         \
        (__attribute__((address_space(1))) void*)(g),                         \
        (__attribute__((address_space(3))) void*)(l), 16, 0, 0)

// ---------------------------------------------------------------------------
// fp32 -> bf16 (RNE) helper
// ---------------------------------------------------------------------------
__device__ inline unsigned f2bf(float x) {
    unsigned u = __float_as_uint(x);
    return (u + 0x7FFFu + ((u >> 16) & 1u)) >> 16;
}

// ---------------------------------------------------------------------------
// Kernel 1: fused bf16 convert + squared L2 row norms. One wave per row
// (64 lanes x 8 floats = 512 = DIM).
// ---------------------------------------------------------------------------
__global__ __launch_bounds__(256) void cvtnorm_k(const float* __restrict__ in,
                                                 unsigned short* __restrict__ outb,
                                                 float* __restrict__ outn,
                                                 int nrows) {
    int row  = blockIdx.x * 4 + (threadIdx.x >> 6);
    int lane = threadIdx.x & 63;
    if (row >= nrows) return;
    const float4* p = (const float4*)(in + (size_t)row * DIM) + lane * 2;
    float4 a = p[0], b = p[1];
    float s = a.x*a.x + a.y*a.y + a.z*a.z + a.w*a.w
            + b.x*b.x + b.y*b.y + b.z*b.z + b.w*b.w;
    uint4 v;
    v.x = f2bf(a.x) | (f2bf(a.y) << 16);
    v.y = f2bf(a.z) | (f2bf(a.w) << 16);
    v.z = f2bf(b.x) | (f2bf(b.y) << 16);
    v.w = f2bf(b.z) | (f2bf(b.w) << 16);
    *((uint4*)(outb + (size_t)row * DIM) + lane) = v;
#pragma unroll
    for (int off = 32; off > 0; off >>= 1) s += __shfl_xor(s, off, 64);
    if (lane == 0) outn[row] = s;
}

// plain norms (fallback path)
__global__ __launch_bounds__(256) void norms_k(const float* __restrict__ X,
                                               float* __restrict__ out,
                                               int nrows) {
    int row  = blockIdx.x * 4 + (threadIdx.x >> 6);
    int lane = threadIdx.x & 63;
    if (row >= nrows) return;
    const float4* xp = (const float4*)(X + (size_t)row * DIM);
    float4 a = xp[lane];
    float4 b = xp[lane + 64];
    float s = a.x*a.x + a.y*a.y + a.z*a.z + a.w*a.w
            + b.x*b.x + b.y*b.y + b.z*b.z + b.w*b.w;
#pragma unroll
    for (int off = 32; off > 0; off >>= 1) s += __shfl_down(s, off, 64);
    if (lane == 0) out[row] = s;
}

// ---------------------------------------------------------------------------
// top-5 insertion (sorted ascending), uint64 keys
// ---------------------------------------------------------------------------
__device__ inline void ins5(unsigned long long key, unsigned long long* top) {
    if (key < top[4]) {
        unsigned long long k0 = top[0], k1 = top[1], k2 = top[2], k3 = top[3];
        top[0] = key < k0 ? key : k0;
        top[1] = key < k0 ? k0 : (key < k1 ? key : k1);
        top[2] = key < k1 ? k1 : (key < k2 ? key : k2);
        top[3] = key < k2 ? k2 : (key < k3 ? key : k3);
        top[4] = key < k3 ? k3 : key;
    }
}

// order-preserving float -> uint map (handles negatives)
__device__ inline unsigned fmono(float v) {
    unsigned u = __float_as_uint(v);
    return (u & 0x80000000u) ? ~u : (u | 0x80000000u);
}

// ---------------------------------------------------------------------------
// Kernel 2: bf16 MFMA distance GEMM + per-(row,seg) approx top-5.
// Block 256 thr (4 waves, 2x2 of 64x64). Tile 128x128, BK=32, double-buffered
// LDS with one-step global_load_lds prefetch (loads for step s+1 issued before
// computing step s; the end-of-step barrier's vmcnt drain then overlaps MFMA).
// v = x2[col] - 2*cross (t2 is row-constant -> irrelevant for ordering).
// ---------------------------------------------------------------------------
__global__ __launch_bounds__(256, 2) void knn_mfma_k(
    const unsigned short* __restrict__ Xtrb,  // bf16 bits [N_TRAIN][DIM]
    const unsigned short* __restrict__ Xteb,  // bf16 bits [N_TEST][DIM]
    const float* __restrict__ x2,
    unsigned long long* __restrict__ cand)    // [N_TEST][NCAND]
{
    __shared__ __align__(16) unsigned short As[2][GTM * GBK];  // 2 x 8 KB
    __shared__ __align__(16) unsigned short Bs[2][GTN * GBK];  // 2 x 8 KB
    __shared__ __align__(16) float Ds[GTM * 68];               // 34 KB (+pad 4)

    const int t     = threadIdx.x;
    const int lane  = t & 63;
    const int w     = t >> 6;
    const int wr    = w >> 1, wc = w & 1;
    const int col_l = lane & 15, quad = lane >> 4;
    const int row0  = blockIdx.x * GTM;
    const int seg0  = blockIdx.y * SEG;

    const int selrow = t >> 1;   // 0..127
    const int selh   = t & 1;    // 32-col half within a 64-col pass

    unsigned long long top[K_NN];
#pragma unroll
    for (int p = 0; p < K_NN; ++p) top[p] = ~0ull;

    // stage step s (col-tile s>>4, k-chunk s&15) into buffer b
    auto stage = [&](int s, int b) {
        const int k0   = (s & 15) * GBK;
        const int col0 = seg0 + (s >> 4) * GTN;
        const int s0 = t, s1 = 256 + t;
        GLDS16(Xteb + (size_t)(row0 + (s0 >> 2)) * DIM + k0 + (s0 & 3) * 8,
               &As[b][(w * 64) * 8]);
        GLDS16(Xteb + (size_t)(row0 + (s1 >> 2)) * DIM + k0 + (s1 & 3) * 8,
               &As[b][(256 + w * 64) * 8]);
        GLDS16(Xtrb + (size_t)(col0 + (s0 >> 2)) * DIM + k0 + (s0 & 3) * 8,
               &Bs[b][(w * 64) * 8]);
        GLDS16(Xtrb + (size_t)(col0 + (s1 >> 2)) * DIM + k0 + (s1 & 3) * 8,
               &Bs[b][(256 + w * 64) * 8]);
    };

    stage(0, 0);
    __syncthreads();   // compiler drains vmcnt(0) before the barrier

    for (int ct = 0; ct < SEG / GTN; ++ct) {
        const int col0 = seg0 + ct * GTN;
        f32x4 acc[4][4];
#pragma unroll
        for (int mt = 0; mt < 4; ++mt)
#pragma unroll
            for (int nt = 0; nt < 4; ++nt)
                acc[mt][nt] = (f32x4){0.f, 0.f, 0.f, 0.f};

#pragma unroll 2
        for (int kk = 0; kk < DIM / GBK; ++kk) {
            const int s = ct * (DIM / GBK) + kk;
            if (s + 1 < NSTEP) stage(s + 1, (s + 1) & 1);  // prefetch next step

            const unsigned short* Ab = As[s & 1];
            const unsigned short* Bb = Bs[s & 1];
            bf16x8 af[4], bfr[4];
#pragma unroll
            for (int mt = 0; mt < 4; ++mt)
                af[mt] = *(const bf16x8*)&Ab[(wr * 64 + mt * 16 + col_l) * GBK + quad * 8];
#pragma unroll
            for (int nt = 0; nt < 4; ++nt)
                bfr[nt] = *(const bf16x8*)&Bb[(wc * 64 + nt * 16 + col_l) * GBK + quad * 8];
#pragma unroll
            for (int mt = 0; mt < 4; ++mt)
#pragma unroll
                for (int nt = 0; nt < 4; ++nt)
                    acc[mt][nt] = __builtin_amdgcn_mfma_f32_16x16x32_bf16(
                        af[mt], bfr[nt], acc[mt][nt], 0, 0, 0);

            __syncthreads();   // drains prefetch (vmcnt) + frag reads (lgkm)
        }

        // epilogue: two 64-col half passes through Ds
#pragma unroll 1
        for (int p = 0; p < 2; ++p) {
            if (wc == p) {
#pragma unroll
                for (int nt = 0; nt < 4; ++nt) {
                    int c = nt * 16 + col_l;                // 0..63 within half
                    float xv = x2[col0 + p * 64 + c];
#pragma unroll
                    for (int mt = 0; mt < 4; ++mt) {
                        int rb = wr * 64 + mt * 16 + quad * 4;
                        f32x4 a = acc[mt][nt];
                        Ds[(rb + 0) * 68 + c] = fmaf(-2.f, a.x, xv);
                        Ds[(rb + 1) * 68 + c] = fmaf(-2.f, a.y, xv);
                        Ds[(rb + 2) * 68 + c] = fmaf(-2.f, a.z, xv);
                        Ds[(rb + 3) * 68 + c] = fmaf(-2.f, a.w, xv);
                    }
                }
            }
            __syncthreads();
            // selection: 2 threads per row, each scans 32 cols of this half
            const int cb = selh * 32;
            const int colbase = col0 + p * 64 + cb;
#pragma unroll
            for (int j = 0; j < 32; j += 4) {
                f32x4 v = *(const f32x4*)&Ds[selrow * 68 + cb + j];
                unsigned long long key;
                key = ((unsigned long long)fmono(v.x) << 32) | (unsigned)(colbase + j + 0);
                ins5(key, top);
                key = ((unsigned long long)fmono(v.y) << 32) | (unsigned)(colbase + j + 1);
                ins5(key, top);
                key = ((unsigned long long)fmono(v.z) << 32) | (unsigned)(colbase + j + 2);
                ins5(key, top);
                key = ((unsigned long long)fmono(v.w) << 32) | (unsigned)(colbase + j + 3);
                ins5(key, top);
            }
            __syncthreads();   // scan done before next pass/ct overwrites Ds
        }
    }

    // merge the two half-selectors per row -> 5 keys per (row, segment)
    unsigned long long* MB2 = (unsigned long long*)Ds;   // 128 rows x 10 u64
#pragma unroll
    for (int p = 0; p < K_NN; ++p) MB2[selrow * 10 + selh * 5 + p] = top[p];
    __syncthreads();
    if (selh == 0) {
        unsigned long long m5[K_NN];
#pragma unroll
        for (int p = 0; p < K_NN; ++p) m5[p] = ~0ull;
#pragma unroll
        for (int i = 0; i < 10; ++i) ins5(MB2[selrow * 10 + i], m5);
        unsigned long long* cr =
            cand + (size_t)(row0 + selrow) * NCAND + blockIdx.y * K_NN;
#pragma unroll
        for (int p = 0; p < K_NN; ++p) cr[p] = m5[p];
    }
}

// ---------------------------------------------------------------------------
// Kernel 3: exact fp32 rescore of the 80 candidates. One wave per test row.
// Overwrites cand keys with ((bits(exact d2)<<32)|col).
// ---------------------------------------------------------------------------
__global__ __launch_bounds__(256) void rescore_k(
    const float* __restrict__ Xtr, const float* __restrict__ Xte,
    const float* __restrict__ x2,  const float* __restrict__ t2,
    unsigned long long* __restrict__ cand)
{
    int row  = blockIdx.x * 4 + (threadIdx.x >> 6);
    int lane = threadIdx.x & 63;
    const float4* te = (const float4*)(Xte + (size_t)row * DIM);
    float4 e0 = te[lane * 2], e1 = te[lane * 2 + 1];
    float t2r = t2[row];
    unsigned long long* cr = cand + (size_t)row * NCAND;

    for (int i = 0; i < NCAND; ++i) {
        unsigned col = (unsigned)(cr[i] & 0xffffffffu);
        const float4* tr = (const float4*)(Xtr + (size_t)col * DIM);
        float4 p = tr[lane * 2], q = tr[lane * 2 + 1];
        float s = e0.x * p.x;
        s = fmaf(e0.y, p.y, s); s = fmaf(e0.z, p.z, s); s = fmaf(e0.w, p.w, s);
        s = fmaf(e1.x, q.x, s); s = fmaf(e1.y, q.y, s);
        s = fmaf(e1.z, q.z, s); s = fmaf(e1.w, q.w, s);
#pragma unroll
        for (int off = 32; off > 0; off >>= 1) s += __shfl_xor(s, off, 64);
        float d2 = fmaxf(t2r + x2[col] - 2.0f * s, 0.0f);
        if (lane == 0)
            cr[i] = ((unsigned long long)__float_as_uint(d2) << 32) | col;
    }
}

// ---------------------------------------------------------------------------
// Kernel 4: exact top-5 of 80 + mode vote (smallest label wins ties).
// ---------------------------------------------------------------------------
__global__ __launch_bounds__(256) void final_k(
    const unsigned long long* __restrict__ cand,
    const int* __restrict__ y, int* __restrict__ out)
{
    int r = blockIdx.x * 256 + threadIdx.x;
    if (r >= N_TEST) return;
    const unsigned long long* cr = cand + (size_t)r * NCAND;

    unsigned long long top[K_NN];
#pragma unroll
    for (int p = 0; p < K_NN; ++p) top[p] = ~0ull;
#pragma unroll 8
    for (int i = 0; i < NCAND; ++i) ins5(cr[i], top);

    int labs[K_NN];
#pragma unroll
    for (int p = 0; p < K_NN; ++p) labs[p] = y[(unsigned)(top[p] & 0xffffffffu)];

    int bestLab = 0x7fffffff, bestCnt = 0;
#pragma unroll
    for (int p = 0; p < K_NN; ++p) {
        int cnt = 0;
#pragma unroll
        for (int q = 0; q < K_NN; ++q) cnt += (labs[q] == labs[p]) ? 1 : 0;
        if (cnt > bestCnt || (cnt == bestCnt && labs[p] < bestLab)) {
            bestCnt = cnt; bestLab = labs[p];
        }
    }
    out[r] = bestLab;
}

// ===========================================================================
// Fallback fp32 path (round-1, verified) in case ws_size is too small.
// Uses its own segmentation: 8 segments, 40 candidates.
// ===========================================================================
#define FTM 64
#define FTN 128
#define FBK 16
#define FSEG (N_TRAIN / 8)

__global__ __launch_bounds__(256) void knn_tile_k(
    const float* __restrict__ Xtr, const float* __restrict__ Xte,
    const float* __restrict__ x2,  const float* __restrict__ t2,
    unsigned long long* __restrict__ cand)
{
    __shared__ float As[FBK][FTM];
    __shared__ float Bs[FBK][FTN];
    __shared__ unsigned long long MB[FTM][16 * K_NN];

    const int t   = threadIdx.x;
    const int ty  = t >> 4;
    const int tx  = t & 15;
    const int row0 = blockIdx.x * FTM;
    const int seg0 = blockIdx.y * FSEG;

    float t2r[4];
#pragma unroll
    for (int j = 0; j < 4; ++j) t2r[j] = t2[row0 + ty * 4 + j];

    unsigned long long top[4][K_NN];
#pragma unroll
    for (int j = 0; j < 4; ++j)
#pragma unroll
        for (int p = 0; p < K_NN; ++p) top[j][p] = ~0ull;

    const int srow = t >> 2;
    const int skq  = (t & 3) * 4;

    for (int ct = 0; ct < FSEG / FTN; ++ct) {
        const int col0 = seg0 + ct * FTN;
        float acc[4][8] = {};

        for (int k0 = 0; k0 < DIM; k0 += FBK) {
            float4 av  = *(const float4*)(Xte + (size_t)(row0 + srow) * DIM + k0 + skq);
            float4 bv0 = *(const float4*)(Xtr + (size_t)(col0 + srow) * DIM + k0 + skq);
            float4 bv1 = *(const float4*)(Xtr + (size_t)(col0 + 64 + srow) * DIM + k0 + skq);
            __syncthreads();
            As[skq + 0][srow] = av.x;  As[skq + 1][srow] = av.y;
            As[skq + 2][srow] = av.z;  As[skq + 3][srow] = av.w;
            Bs[skq + 0][srow] = bv0.x; Bs[skq + 1][srow] = bv0.y;
            Bs[skq + 2][srow] = bv0.z; Bs[skq + 3][srow] = bv0.w;
            Bs[skq + 0][srow + 64] = bv1.x; Bs[skq + 1][srow + 64] = bv1.y;
            Bs[skq + 2][srow + 64] = bv1.z; Bs[skq + 3][srow + 64] = bv1.w;
            __syncthreads();

#pragma unroll
            for (int k = 0; k < FBK; ++k) {
                float4 a  = *(const float4*)&As[k][ty * 4];
                float4 b0 = *(const float4*)&Bs[k][tx * 8];
                float4 b1 = *(const float4*)&Bs[k][tx * 8 + 4];
                float a4[4] = {a.x, a.y, a.z, a.w};
                float b8[8] = {b0.x, b0.y, b0.z, b0.w, b1.x, b1.y, b1.z, b1.w};
#pragma unroll
                for (int j = 0; j < 4; ++j)
#pragma unroll
                    for (int l = 0; l < 8; ++l)
                        acc[j][l] = fmaf(a4[j], b8[l], acc[j][l]);
            }
        }

#pragma unroll
        for (int j = 0; j < 4; ++j) {
#pragma unroll
            for (int l = 0; l < 8; ++l) {
                int col = col0 + tx * 8 + l;
                float d2 = fmaxf(t2r[j] + x2[col] - 2.0f * acc[j][l], 0.0f);
                unsigned long long key =
                    ((unsigned long long)__float_as_uint(d2) << 32) | (unsigned)col;
                ins5(key, top[j]);
            }
        }
    }

#pragma unroll
    for (int j = 0; j < 4; ++j)
#pragma unroll
        for (int p = 0; p < K_NN; ++p)
            MB[ty * 4 + j][tx * K_NN + p] = top[j][p];
    __syncthreads();

    if (t < FTM) {
        unsigned long long last = 0;
        for (int p = 0; p < K_NN; ++p) {
            unsigned long long best = ~0ull;
            for (int q = 0; q < 16 * K_NN; ++q) {
                unsigned long long v = MB[t][q];
                if (v > last && v < best) best = v;
            }
            cand[(size_t)(row0 + t) * 40 + blockIdx.y * K_NN + p] = best;
            last = best;
        }
    }
}

__global__ __launch_bounds__(256) void knn_final_k(
    const unsigned long long* __restrict__ cand,
    const int* __restrict__ y, int* __restrict__ out)
{
    int r = blockIdx.x * 256 + threadIdx.x;
    if (r >= N_TEST) return;
    const unsigned long long* c = cand + (size_t)r * 40;

    unsigned long long top[K_NN];
#pragma unroll
    for (int p = 0; p < K_NN; ++p) top[p] = ~0ull;
#pragma unroll
    for (int i = 0; i < 40; ++i) ins5(c[i], top);

    int labs[K_NN];
#pragma unroll
    for (int p = 0; p < K_NN; ++p) labs[p] = y[(unsigned)(top[p] & 0xffffffffu)];

    int bestLab = 0x7fffffff, bestCnt = 0;
#pragma unroll
    for (int p = 0; p < K_NN; ++p) {
        int cnt = 0;
#pragma unroll
        for (int q = 0; q < K_NN; ++q) cnt += (labs[q] == labs[p]) ? 1 : 0;
        if (cnt > bestCnt || (cnt == bestCnt && labs[p] < bestLab)) {
            bestCnt = cnt; bestLab = labs[p];
        }
    }
    out[r] = bestLab;
}

// ---------------------------------------------------------------------------
// Workspace layout (MFMA path), bytes:
//   [0,        262144)   x2     : 65536 f32
//   [262144,   278528)   t2     : 4096 f32
//   [278528,  2899968)   cand   : 4096 * 80 u64
//   [3145728, 7340032)   Xte_bf : 4096*512 bf16
//   [7340032, 74448896)  Xtr_bf : 65536*512 bf16
// ---------------------------------------------------------------------------
extern "C" void kernel_launch(void* const* d_in, const int* in_sizes, int n_in,
                              void* d_out, int out_size, void* d_ws, size_t ws_size,
                              hipStream_t stream) {
    const float* Xtr = (const float*)d_in[0];
    const float* Xte = (const float*)d_in[1];
    const int*   y   = (const int*)d_in[2];
    int* out = (int*)d_out;

    char* ws = (char*)d_ws;
    float* x2 = (float*)ws;
    float* t2 = (float*)(ws + 262144);
    unsigned long long* cand = (unsigned long long*)(ws + 278528);

    const size_t NEED = 74448896;

    if (ws_size >= NEED) {
        unsigned short* Xteb = (unsigned short*)(ws + 3145728);
        unsigned short* Xtrb = (unsigned short*)(ws + 7340032);

        cvtnorm_k<<<N_TRAIN / 4, 256, 0, stream>>>(Xtr, Xtrb, x2, N_TRAIN);
        cvtnorm_k<<<N_TEST / 4, 256, 0, stream>>>(Xte, Xteb, t2, N_TEST);

        knn_mfma_k<<<dim3(N_TEST / GTM, NSEG), 256, 0, stream>>>(Xtrb, Xteb, x2, cand);
        rescore_k<<<N_TEST / 4, 256, 0, stream>>>(Xtr, Xte, x2, t2, cand);
        final_k<<<N_TEST / 256, 256, 0, stream>>>(cand, y, out);
    } else {
        // fp32 fallback (round-1 verified path); cand here is [N_TEST][40]
        norms_k<<<N_TRAIN / 4, 256, 0, stream>>>(Xtr, x2, N_TRAIN);
        norms_k<<<N_TEST / 4, 256, 0, stream>>>(Xte, t2, N_TEST);
        knn_tile_k<<<dim3(N_TEST / FTM, 8), 256, 0, stream>>>(Xtr, Xte, x2, t2, cand);
        knn_final_k<<<N_TEST / 256, 256, 0, stream>>>(cand, y, out);
    }
}